// Round 1
// baseline (13891.818 us; speedup 1.0000x reference)
//
#include <hip/hip_runtime.h>
#include <cstdint>
#include <cstddef>

// Problem: tanh-RNN (SlimeMoldEncoder): S=1024 steps, B=32 batch, D=1024.
//   h_t = tanh(src[t] @ W_in + h_{t-1} @ W_rec + b_h);  out[t] = h_t @ W_out + b_o
// Strategy:
//   1) Xpre = src @ W_in + b_h           (big bf16 MFMA GEMM, fp32 out)
//   2) 1024x step kernels: h_{t+1} = tanh(Xpre[t] + h_t @ W_rec)  (bf16 MFMA)
//   3) out  = H @ W_out + b_o            (big bf16 MFMA GEMM)
// Weights pre-transposed to [N,K] bf16 so MFMA B-fragments are contiguous.

#define S_LEN 1024
#define B_SZ  32
#define D_MOD 1024
#define M_TOT (S_LEN * B_SZ)  // 32768

typedef __attribute__((ext_vector_type(8))) short    short8;   // 8 bf16 (4 VGPRs)
typedef __attribute__((ext_vector_type(4))) float    floatx4;  // MFMA acc

// ---- bf16 helpers (bit-level, no hip_bf16 API dependence) ----
__device__ __forceinline__ unsigned short f2bf(float f) {
  unsigned int u = __float_as_uint(f);
  unsigned int lsb = (u >> 16) & 1u;
  u += 0x7fffu + lsb;  // round-to-nearest-even
  return (unsigned short)(u >> 16);
}

// ---- src f32 -> bf16 (vectorized) ----
__global__ __launch_bounds__(256) void convert_src_kernel(
    const float* __restrict__ in, unsigned short* __restrict__ out, int n) {
  int idx = (blockIdx.x * 256 + threadIdx.x) * 4;
  if (idx < n) {
    float4 v = *reinterpret_cast<const float4*>(in + idx);
    ushort4 o;
    o.x = f2bf(v.x); o.y = f2bf(v.y); o.z = f2bf(v.z); o.w = f2bf(v.w);
    *reinterpret_cast<ushort4*>(out + idx) = o;
  }
}

// ---- W [K=1024][N=1024] f32  ->  Wt [N][K] bf16 (tiled transpose) ----
__global__ __launch_bounds__(256) void transpose_w_kernel(
    const float* __restrict__ in, unsigned short* __restrict__ out) {
  __shared__ float tile[32][33];
  const int tx = threadIdx.x & 31;
  const int ty = threadIdx.x >> 5;  // 0..7
  const int kb = blockIdx.x * 32;
  const int nb = blockIdx.y * 32;
#pragma unroll
  for (int r = 0; r < 32; r += 8)
    tile[ty + r][tx] = in[(size_t)(kb + ty + r) * D_MOD + nb + tx];
  __syncthreads();
#pragma unroll
  for (int r = 0; r < 32; r += 8)
    out[(size_t)(nb + ty + r) * D_MOD + kb + tx] = f2bf(tile[tx][ty + r]);
}

// ---- big GEMM: C[M,N] f32 = A[M,K]bf16 @ Bt[N,K]bf16^T + bias[N] ----
// 128x128 tile, 256 threads = 4 waves (2x2), each wave 64x64 = 4x4 16x16 frags.
#define BM 128
#define BN 128
#define BK 32

__global__ __launch_bounds__(256) void gemm_bias_kernel(
    const unsigned short* __restrict__ A,   // [M,K]
    const unsigned short* __restrict__ Bt,  // [N,K]
    const float* __restrict__ bias,         // [N]
    float* __restrict__ C,                  // [M,N]
    int M, int N, int K) {
  __shared__ unsigned short Asl[BM * BK];
  __shared__ unsigned short Bsl[BN * BK];
  const int tid  = threadIdx.x;
  const int lane = tid & 63;
  const int wave = tid >> 6;
  const int wm = wave >> 1, wn = wave & 1;
  const int m0 = blockIdx.y * BM;
  const int n0 = blockIdx.x * BN;

  floatx4 acc[4][4] = {};

  const int r0  = tid >> 2;       // 0..63
  const int sl0 = (tid & 3) * 8;  // k-part within row

  for (int ko = 0; ko < K; ko += BK) {
    // stage A (rows r0, r0+64) and B tiles: 16B per thread per piece
    *reinterpret_cast<short8*>(&Asl[(r0)      * BK + sl0]) =
        *reinterpret_cast<const short8*>(&A[(size_t)(m0 + r0)      * K + ko + sl0]);
    *reinterpret_cast<short8*>(&Asl[(r0 + 64) * BK + sl0]) =
        *reinterpret_cast<const short8*>(&A[(size_t)(m0 + r0 + 64) * K + ko + sl0]);
    *reinterpret_cast<short8*>(&Bsl[(r0)      * BK + sl0]) =
        *reinterpret_cast<const short8*>(&Bt[(size_t)(n0 + r0)      * K + ko + sl0]);
    *reinterpret_cast<short8*>(&Bsl[(r0 + 64) * BK + sl0]) =
        *reinterpret_cast<const short8*>(&Bt[(size_t)(n0 + r0 + 64) * K + ko + sl0]);
    __syncthreads();

    const int kr = (lane >> 4) * 8;
    short8 af[4], bf[4];
#pragma unroll
    for (int i = 0; i < 4; ++i)
      af[i] = *reinterpret_cast<const short8*>(&Asl[(wm * 64 + i * 16 + (lane & 15)) * BK + kr]);
#pragma unroll
    for (int j = 0; j < 4; ++j)
      bf[j] = *reinterpret_cast<const short8*>(&Bsl[(wn * 64 + j * 16 + (lane & 15)) * BK + kr]);
#pragma unroll
    for (int i = 0; i < 4; ++i)
#pragma unroll
      for (int j = 0; j < 4; ++j)
        acc[i][j] = __builtin_amdgcn_mfma_f32_16x16x32_bf16(af[i], bf[j], acc[i][j], 0, 0, 0);
    __syncthreads();
  }

  const int cl = lane & 15, rq = lane >> 4;
#pragma unroll
  for (int i = 0; i < 4; ++i) {
#pragma unroll
    for (int j = 0; j < 4; ++j) {
      const int n = n0 + wn * 64 + j * 16 + cl;
      const float bs = bias[n];
#pragma unroll
      for (int r = 0; r < 4; ++r) {
        const int m = m0 + wm * 64 + i * 16 + rq * 4 + r;
        C[(size_t)m * N + n] = acc[i][j][r] + bs;
      }
    }
  }
}

// ---- recurrence step: Hnew[32,1024] = tanh(Xpre_t + Hprev @ W_rec) ----
// 64 blocks x 64 threads (1 wave). Block b computes cols [16b, 16b+16).
__global__ __launch_bounds__(64) void step_kernel(
    const unsigned short* __restrict__ Hprev,  // [32,1024] bf16
    const unsigned short* __restrict__ Wrt,    // Wt_rec [N,K] bf16
    const float* __restrict__ Xpre_t,          // [32,1024] f32
    unsigned short* __restrict__ Hnew) {       // [32,1024] bf16
  const int lane = threadIdx.x;
  const int n0 = blockIdx.x * 16;
  const int cl = lane & 15;
  const int kr = (lane >> 4) * 8;
  floatx4 acc0 = {}, acc1 = {};
#pragma unroll 4
  for (int ko = 0; ko < D_MOD; ko += 32) {
    short8 a0 = *reinterpret_cast<const short8*>(&Hprev[(size_t)cl        * D_MOD + ko + kr]);
    short8 a1 = *reinterpret_cast<const short8*>(&Hprev[(size_t)(16 + cl) * D_MOD + ko + kr]);
    short8 b  = *reinterpret_cast<const short8*>(&Wrt[(size_t)(n0 + cl)   * D_MOD + ko + kr]);
    acc0 = __builtin_amdgcn_mfma_f32_16x16x32_bf16(a0, b, acc0, 0, 0, 0);
    acc1 = __builtin_amdgcn_mfma_f32_16x16x32_bf16(a1, b, acc1, 0, 0, 0);
  }
  const int rq = lane >> 4;
#pragma unroll
  for (int r = 0; r < 4; ++r) {
    int m = rq * 4 + r;
    const int n = n0 + cl;
    float h = tanhf(acc0[r] + Xpre_t[m * D_MOD + n]);
    Hnew[m * D_MOD + n] = f2bf(h);
    m += 16;
    float h2 = tanhf(acc1[r] + Xpre_t[m * D_MOD + n]);
    Hnew[m * D_MOD + n] = f2bf(h2);
  }
}

extern "C" void kernel_launch(void* const* d_in, const int* in_sizes, int n_in,
                              void* d_out, int out_size, void* d_ws, size_t ws_size,
                              hipStream_t stream) {
  const float* src   = (const float*)d_in[0];
  const float* W_in  = (const float*)d_in[1];
  const float* W_rec = (const float*)d_in[2];
  const float* W_out = (const float*)d_in[3];
  const float* b_h   = (const float*)d_in[4];
  const float* b_o   = (const float*)d_in[5];
  float* out = (float*)d_out;

  // workspace layout (~262 MB total)
  char* ws = (char*)d_ws;
  unsigned short* src_bf = (unsigned short*)ws; ws += (size_t)M_TOT * D_MOD * 2;
  unsigned short* Wt_in  = (unsigned short*)ws; ws += (size_t)D_MOD * D_MOD * 2;
  unsigned short* Wt_rec = (unsigned short*)ws; ws += (size_t)D_MOD * D_MOD * 2;
  unsigned short* Wt_out = (unsigned short*)ws; ws += (size_t)D_MOD * D_MOD * 2;
  float*          Xpre   = (float*)ws;          ws += (size_t)M_TOT * D_MOD * 4;
  unsigned short* Hext   = (unsigned short*)ws; // [(S+1), 32, 1024] bf16; slot 0 = h0 = 0

  convert_src_kernel<<<(M_TOT * D_MOD / 4 + 255) / 256, 256, 0, stream>>>(
      src, src_bf, M_TOT * D_MOD);
  dim3 tg(32, 32);
  transpose_w_kernel<<<tg, 256, 0, stream>>>(W_in,  Wt_in);
  transpose_w_kernel<<<tg, 256, 0, stream>>>(W_rec, Wt_rec);
  transpose_w_kernel<<<tg, 256, 0, stream>>>(W_out, Wt_out);
  hipMemsetAsync(Hext, 0, (size_t)B_SZ * D_MOD * 2, stream);

  dim3 g1(D_MOD / BN, M_TOT / BM);  // (8, 256)
  gemm_bias_kernel<<<g1, 256, 0, stream>>>(src_bf, Wt_in, b_h, Xpre, M_TOT, D_MOD, D_MOD);

  for (int t = 0; t < S_LEN; ++t) {
    step_kernel<<<64, 64, 0, stream>>>(
        Hext + (size_t)t * B_SZ * D_MOD, Wt_rec,
        Xpre + (size_t)t * B_SZ * D_MOD,
        Hext + (size_t)(t + 1) * B_SZ * D_MOD);
  }

  gemm_bias_kernel<<<g1, 256, 0, stream>>>(
      Hext + (size_t)B_SZ * D_MOD, Wt_out, b_o, out, M_TOT, D_MOD, D_MOD);
}

// Round 2
// 12049.412 us; speedup vs baseline: 1.1529x; 1.1529x over previous
//
#include <hip/hip_runtime.h>
#include <cstdint>
#include <cstddef>

// tanh-RNN (SlimeMoldEncoder): S=1024, B=32, D=1024.
//   h_t = tanh(src[t]@W_in + h_{t-1}@W_rec + b_h);  out[t] = h_t@W_out + b_o
// R2: recurrence as ONE persistent kernel (32 blocks x 1 wave) with a
// device-scope atomic grid barrier; W_rec slice staged in LDS (frag order).

#define S_LEN 1024
#define B_SZ  32
#define D_MOD 1024
#define M_TOT (S_LEN * B_SZ)  // 32768
#define NBLK  32              // rnn blocks; each owns 32 columns

typedef __attribute__((ext_vector_type(8))) short    short8;   // 8 bf16
typedef __attribute__((ext_vector_type(4))) float    floatx4;  // MFMA acc

__device__ __forceinline__ unsigned short f2bf(float f) {
  unsigned int u = __float_as_uint(f);
  unsigned int lsb = (u >> 16) & 1u;
  u += 0x7fffu + lsb;  // RNE
  return (unsigned short)(u >> 16);
}

__device__ __forceinline__ float tanh_fast(float x) {
  // clamp so exp never overflows; tanh(9) = 1 - 2.7e-8, below bf16 resolution
  float xc = fminf(fmaxf(x, -9.f), 9.f);
  float e  = __expf(2.f * xc);
  return 1.f - 2.f / (e + 1.f);
}

// ---- src f32 -> bf16 ----
__global__ __launch_bounds__(256) void convert_src_kernel(
    const float* __restrict__ in, unsigned short* __restrict__ out, int n) {
  int idx = (blockIdx.x * 256 + threadIdx.x) * 4;
  if (idx < n) {
    float4 v = *reinterpret_cast<const float4*>(in + idx);
    ushort4 o;
    o.x = f2bf(v.x); o.y = f2bf(v.y); o.z = f2bf(v.z); o.w = f2bf(v.w);
    *reinterpret_cast<ushort4*>(out + idx) = o;
  }
}

// ---- W [K][N] f32 -> Wt [N][K] bf16 ----
__global__ __launch_bounds__(256) void transpose_w_kernel(
    const float* __restrict__ in, unsigned short* __restrict__ out) {
  __shared__ float tile[32][33];
  const int tx = threadIdx.x & 31;
  const int ty = threadIdx.x >> 5;
  const int kb = blockIdx.x * 32;
  const int nb = blockIdx.y * 32;
#pragma unroll
  for (int r = 0; r < 32; r += 8)
    tile[ty + r][tx] = in[(size_t)(kb + ty + r) * D_MOD + nb + tx];
  __syncthreads();
#pragma unroll
  for (int r = 0; r < 32; r += 8)
    out[(size_t)(nb + ty + r) * D_MOD + kb + tx] = f2bf(tile[tx][ty + r]);
}

// ---- big GEMM: C[M,N] f32 = A[M,K]bf16 @ Bt[N,K]^T + bias ----
#define BM 128
#define BN 128
#define BK 32

__global__ __launch_bounds__(256) void gemm_bias_kernel(
    const unsigned short* __restrict__ A,
    const unsigned short* __restrict__ Bt,
    const float* __restrict__ bias,
    float* __restrict__ C,
    int M, int N, int K) {
  __shared__ unsigned short Asl[BM * BK];
  __shared__ unsigned short Bsl[BN * BK];
  const int tid  = threadIdx.x;
  const int lane = tid & 63;
  const int wave = tid >> 6;
  const int wm = wave >> 1, wn = wave & 1;
  const int m0 = blockIdx.y * BM;
  const int n0 = blockIdx.x * BN;

  floatx4 acc[4][4] = {};
  const int r0  = tid >> 2;
  const int sl0 = (tid & 3) * 8;

  for (int ko = 0; ko < K; ko += BK) {
    *reinterpret_cast<short8*>(&Asl[(r0)      * BK + sl0]) =
        *reinterpret_cast<const short8*>(&A[(size_t)(m0 + r0)      * K + ko + sl0]);
    *reinterpret_cast<short8*>(&Asl[(r0 + 64) * BK + sl0]) =
        *reinterpret_cast<const short8*>(&A[(size_t)(m0 + r0 + 64) * K + ko + sl0]);
    *reinterpret_cast<short8*>(&Bsl[(r0)      * BK + sl0]) =
        *reinterpret_cast<const short8*>(&Bt[(size_t)(n0 + r0)      * K + ko + sl0]);
    *reinterpret_cast<short8*>(&Bsl[(r0 + 64) * BK + sl0]) =
        *reinterpret_cast<const short8*>(&Bt[(size_t)(n0 + r0 + 64) * K + ko + sl0]);
    __syncthreads();

    const int kr = (lane >> 4) * 8;
    short8 af[4], bf[4];
#pragma unroll
    for (int i = 0; i < 4; ++i)
      af[i] = *reinterpret_cast<const short8*>(&Asl[(wm * 64 + i * 16 + (lane & 15)) * BK + kr]);
#pragma unroll
    for (int j = 0; j < 4; ++j)
      bf[j] = *reinterpret_cast<const short8*>(&Bsl[(wn * 64 + j * 16 + (lane & 15)) * BK + kr]);
#pragma unroll
    for (int i = 0; i < 4; ++i)
#pragma unroll
      for (int j = 0; j < 4; ++j)
        acc[i][j] = __builtin_amdgcn_mfma_f32_16x16x32_bf16(af[i], bf[j], acc[i][j], 0, 0, 0);
    __syncthreads();
  }

  const int cl = lane & 15, rq = lane >> 4;
#pragma unroll
  for (int i = 0; i < 4; ++i) {
#pragma unroll
    for (int j = 0; j < 4; ++j) {
      const int n = n0 + wn * 64 + j * 16 + cl;
      const float bs = bias[n];
#pragma unroll
      for (int r = 0; r < 4; ++r) {
        const int m = m0 + wm * 64 + i * 16 + rq * 4 + r;
        C[(size_t)m * N + n] = acc[i][j][r] + bs;
      }
    }
  }
}

// ---- persistent recurrence kernel ----
// 32 blocks x 64 threads. Block b owns columns [32b, 32b+32).
// W_rec slice staged ONCE in LDS in MFMA-fragment order (conflict-free reads).
// Grid barrier: monotonic global counter, release-arrive / acquire-spin.
__global__ __launch_bounds__(64) void rnn_kernel(
    const unsigned short* __restrict__ Wrt,   // [N][K] bf16
    const float* __restrict__ Xpre,           // [S][32][1024] f32
    unsigned short* __restrict__ Hext,        // [(S+1)][32][1024] bf16
    int* __restrict__ cnt) {
  __shared__ unsigned short wlds[NBLK * 1024 * 2 / 2 * 2];  // 32 cols * 1024 K = 64 KB
  const int lane = threadIdx.x;
  const int cl   = lane & 15;
  const int rq   = lane >> 4;
  const int kr8  = rq * 8;
  const int n0   = blockIdx.x * 32;

  // stage W fragments: lds slot ((g*2+j)*64 + lane) holds 8 bf16 of
  // row n0+j*16+cl, k = g*32 + kr8 .. +8
#pragma unroll 4
  for (int g = 0; g < 32; ++g) {
#pragma unroll
    for (int j = 0; j < 2; ++j) {
      const int n = n0 + j * 16 + cl;
      const int k = g * 32 + kr8;
      *reinterpret_cast<short8*>(&wlds[(size_t)((g * 2 + j) * 64 + lane) * 8]) =
          *reinterpret_cast<const short8*>(&Wrt[(size_t)n * D_MOD + k]);
    }
  }
  __syncthreads();

  // prefetch Xpre quad for t=0
  float xq[16];
#pragma unroll
  for (int j = 0; j < 2; ++j)
#pragma unroll
    for (int h = 0; h < 2; ++h)
#pragma unroll
      for (int r = 0; r < 4; ++r)
        xq[j * 8 + h * 4 + r] =
            Xpre[(size_t)(h * 16 + rq * 4 + r) * D_MOD + n0 + j * 16 + cl];

#pragma unroll 1
  for (int t = 0; t < S_LEN; ++t) {
    if (t > 0) {
      const int target = NBLK * t;
      while (__hip_atomic_load(cnt, __ATOMIC_ACQUIRE, __HIP_MEMORY_SCOPE_AGENT) < target)
        __builtin_amdgcn_s_sleep(1);
    }
    const unsigned short* __restrict__ Hp = Hext + (size_t)t * B_SZ * D_MOD;

    floatx4 acc[2][2] = {};
#pragma unroll 8
    for (int g = 0; g < 32; ++g) {
      short8 a0 = *reinterpret_cast<const short8*>(&Hp[(size_t)cl        * D_MOD + g * 32 + kr8]);
      short8 a1 = *reinterpret_cast<const short8*>(&Hp[(size_t)(16 + cl) * D_MOD + g * 32 + kr8]);
      short8 b0 = *reinterpret_cast<const short8*>(&wlds[(size_t)((g * 2 + 0) * 64 + lane) * 8]);
      short8 b1 = *reinterpret_cast<const short8*>(&wlds[(size_t)((g * 2 + 1) * 64 + lane) * 8]);
      acc[0][0] = __builtin_amdgcn_mfma_f32_16x16x32_bf16(a0, b0, acc[0][0], 0, 0, 0);
      acc[0][1] = __builtin_amdgcn_mfma_f32_16x16x32_bf16(a1, b0, acc[0][1], 0, 0, 0);
      acc[1][0] = __builtin_amdgcn_mfma_f32_16x16x32_bf16(a0, b1, acc[1][0], 0, 0, 0);
      acc[1][1] = __builtin_amdgcn_mfma_f32_16x16x32_bf16(a1, b1, acc[1][1], 0, 0, 0);
    }

    unsigned short* __restrict__ Hn = Hext + (size_t)(t + 1) * B_SZ * D_MOD;
#pragma unroll
    for (int j = 0; j < 2; ++j)
#pragma unroll
      for (int h = 0; h < 2; ++h)
#pragma unroll
        for (int r = 0; r < 4; ++r) {
          const int m = h * 16 + rq * 4 + r;
          const int n = n0 + j * 16 + cl;
          float v = tanh_fast(acc[j][h][r] + xq[j * 8 + h * 4 + r]);
          Hn[(size_t)m * D_MOD + n] = f2bf(v);
        }

    if (lane == 0)
      __hip_atomic_fetch_add(cnt, 1, __ATOMIC_RELEASE, __HIP_MEMORY_SCOPE_AGENT);

    // prefetch next step's Xpre during barrier wait; pin issue point
    if (t < S_LEN - 1) {
      const float* __restrict__ Xt = Xpre + (size_t)(t + 1) * B_SZ * D_MOD;
#pragma unroll
      for (int j = 0; j < 2; ++j)
#pragma unroll
        for (int h = 0; h < 2; ++h)
#pragma unroll
          for (int r = 0; r < 4; ++r) {
            float v = Xt[(size_t)(h * 16 + rq * 4 + r) * D_MOD + n0 + j * 16 + cl];
            asm volatile("" : "+v"(v));
            xq[j * 8 + h * 4 + r] = v;
          }
    }
  }
}

extern "C" void kernel_launch(void* const* d_in, const int* in_sizes, int n_in,
                              void* d_out, int out_size, void* d_ws, size_t ws_size,
                              hipStream_t stream) {
  const float* src   = (const float*)d_in[0];
  const float* W_in  = (const float*)d_in[1];
  const float* W_rec = (const float*)d_in[2];
  const float* W_out = (const float*)d_in[3];
  const float* b_h   = (const float*)d_in[4];
  const float* b_o   = (const float*)d_in[5];
  float* out = (float*)d_out;

  char* ws = (char*)d_ws;
  unsigned short* src_bf = (unsigned short*)ws; ws += (size_t)M_TOT * D_MOD * 2;
  unsigned short* Wt_in  = (unsigned short*)ws; ws += (size_t)D_MOD * D_MOD * 2;
  unsigned short* Wt_rec = (unsigned short*)ws; ws += (size_t)D_MOD * D_MOD * 2;
  unsigned short* Wt_out = (unsigned short*)ws; ws += (size_t)D_MOD * D_MOD * 2;
  float*          Xpre   = (float*)ws;          ws += (size_t)M_TOT * D_MOD * 4;
  unsigned short* Hext   = (unsigned short*)ws; ws += (size_t)(S_LEN + 1) * B_SZ * D_MOD * 2;
  int*            cnt    = (int*)ws;            // barrier counter (128B-aligned region)

  convert_src_kernel<<<(M_TOT * D_MOD / 4 + 255) / 256, 256, 0, stream>>>(
      src, src_bf, M_TOT * D_MOD);
  dim3 tg(32, 32);
  transpose_w_kernel<<<tg, 256, 0, stream>>>(W_in,  Wt_in);
  transpose_w_kernel<<<tg, 256, 0, stream>>>(W_rec, Wt_rec);
  transpose_w_kernel<<<tg, 256, 0, stream>>>(W_out, Wt_out);
  hipMemsetAsync(Hext, 0, (size_t)B_SZ * D_MOD * 2, stream);  // h0 = 0
  hipMemsetAsync(cnt, 0, 128, stream);                        // barrier counter = 0

  dim3 g1(D_MOD / BN, M_TOT / BM);
  gemm_bias_kernel<<<g1, 256, 0, stream>>>(src_bf, Wt_in, b_h, Xpre, M_TOT, D_MOD, D_MOD);

  rnn_kernel<<<NBLK, 64, 0, stream>>>(Wt_rec, Xpre, Hext, cnt);

  gemm_bias_kernel<<<g1, 256, 0, stream>>>(
      Hext + (size_t)B_SZ * D_MOD, Wt_out, b_o, out, M_TOT, D_MOD, D_MOD);
}

// Round 3
// 5648.540 us; speedup vs baseline: 2.4594x; 2.1332x over previous
//
#include <hip/hip_runtime.h>
#include <cstdint>
#include <cstddef>

// tanh-RNN (SlimeMoldEncoder): S=1024, B=32, D=1024.
//   h_t = tanh(src[t]@W_in + h_{t-1}@W_rec + b_h);  out[t] = h_t@W_out + b_o
// R3: persistent recurrence, 32 blocks x 4 waves (K-split). Cross-XCD traffic
// via relaxed SYSTEM-scope 8B atomics (sc0 sc1 cache-bypass -> IF$) — no
// buffer_wbl2 / buffer_inv cache maintenance. Per-block flag array barrier.

#define S_LEN 1024
#define B_SZ  32
#define D_MOD 1024
#define M_TOT (S_LEN * B_SZ)  // 32768
#define NBLK  32              // rnn blocks; each owns 32 columns

typedef __attribute__((ext_vector_type(8))) short    short8;   // 8 bf16
typedef __attribute__((ext_vector_type(4))) float    floatx4;  // MFMA acc

__device__ __forceinline__ unsigned short f2bf(float f) {
  unsigned int u = __float_as_uint(f);
  unsigned int lsb = (u >> 16) & 1u;
  u += 0x7fffu + lsb;  // RNE
  return (unsigned short)(u >> 16);
}

__device__ __forceinline__ float tanh_fast(float x) {
  float xc = fminf(fmaxf(x, -9.f), 9.f);
  float e  = __expf(2.f * xc);
  return 1.f - 2.f / (e + 1.f);
}

// ---- src f32 -> bf16 ----
__global__ __launch_bounds__(256) void convert_src_kernel(
    const float* __restrict__ in, unsigned short* __restrict__ out, int n) {
  int idx = (blockIdx.x * 256 + threadIdx.x) * 4;
  if (idx < n) {
    float4 v = *reinterpret_cast<const float4*>(in + idx);
    ushort4 o;
    o.x = f2bf(v.x); o.y = f2bf(v.y); o.z = f2bf(v.z); o.w = f2bf(v.w);
    *reinterpret_cast<ushort4*>(out + idx) = o;
  }
}

// ---- W [K][N] f32 -> Wt [N][K] bf16 ----
__global__ __launch_bounds__(256) void transpose_w_kernel(
    const float* __restrict__ in, unsigned short* __restrict__ out) {
  __shared__ float tile[32][33];
  const int tx = threadIdx.x & 31;
  const int ty = threadIdx.x >> 5;
  const int kb = blockIdx.x * 32;
  const int nb = blockIdx.y * 32;
#pragma unroll
  for (int r = 0; r < 32; r += 8)
    tile[ty + r][tx] = in[(size_t)(kb + ty + r) * D_MOD + nb + tx];
  __syncthreads();
#pragma unroll
  for (int r = 0; r < 32; r += 8)
    out[(size_t)(nb + ty + r) * D_MOD + kb + tx] = f2bf(tile[tx][ty + r]);
}

// ---- big GEMM: C[M,N] f32 = A[M,K]bf16 @ Bt[N,K]^T + bias ----
#define BM 128
#define BN 128
#define BK 32

__global__ __launch_bounds__(256) void gemm_bias_kernel(
    const unsigned short* __restrict__ A,
    const unsigned short* __restrict__ Bt,
    const float* __restrict__ bias,
    float* __restrict__ C,
    int M, int N, int K) {
  __shared__ unsigned short Asl[BM * BK];
  __shared__ unsigned short Bsl[BN * BK];
  const int tid  = threadIdx.x;
  const int lane = tid & 63;
  const int wave = tid >> 6;
  const int wm = wave >> 1, wn = wave & 1;
  const int m0 = blockIdx.y * BM;
  const int n0 = blockIdx.x * BN;

  floatx4 acc[4][4] = {};
  const int r0  = tid >> 2;
  const int sl0 = (tid & 3) * 8;

  for (int ko = 0; ko < K; ko += BK) {
    *reinterpret_cast<short8*>(&Asl[(r0)      * BK + sl0]) =
        *reinterpret_cast<const short8*>(&A[(size_t)(m0 + r0)      * K + ko + sl0]);
    *reinterpret_cast<short8*>(&Asl[(r0 + 64) * BK + sl0]) =
        *reinterpret_cast<const short8*>(&A[(size_t)(m0 + r0 + 64) * K + ko + sl0]);
    *reinterpret_cast<short8*>(&Bsl[(r0)      * BK + sl0]) =
        *reinterpret_cast<const short8*>(&Bt[(size_t)(n0 + r0)      * K + ko + sl0]);
    *reinterpret_cast<short8*>(&Bsl[(r0 + 64) * BK + sl0]) =
        *reinterpret_cast<const short8*>(&Bt[(size_t)(n0 + r0 + 64) * K + ko + sl0]);
    __syncthreads();

    const int kr = (lane >> 4) * 8;
    short8 af[4], bf[4];
#pragma unroll
    for (int i = 0; i < 4; ++i)
      af[i] = *reinterpret_cast<const short8*>(&Asl[(wm * 64 + i * 16 + (lane & 15)) * BK + kr]);
#pragma unroll
    for (int j = 0; j < 4; ++j)
      bf[j] = *reinterpret_cast<const short8*>(&Bsl[(wn * 64 + j * 16 + (lane & 15)) * BK + kr]);
#pragma unroll
    for (int i = 0; i < 4; ++i)
#pragma unroll
      for (int j = 0; j < 4; ++j)
        acc[i][j] = __builtin_amdgcn_mfma_f32_16x16x32_bf16(af[i], bf[j], acc[i][j], 0, 0, 0);
    __syncthreads();
  }

  const int cl = lane & 15, rq = lane >> 4;
#pragma unroll
  for (int i = 0; i < 4; ++i) {
#pragma unroll
    for (int j = 0; j < 4; ++j) {
      const int n = n0 + wn * 64 + j * 16 + cl;
      const float bs = bias[n];
#pragma unroll
      for (int r = 0; r < 4; ++r) {
        const int m = m0 + wm * 64 + i * 16 + rq * 4 + r;
        C[(size_t)m * N + n] = acc[i][j][r] + bs;
      }
    }
  }
}

// ---- persistent recurrence: 32 blocks x 256 threads (4 waves, K-split) ----
// Block b owns output cols [32b, 32b+32). Wave w handles K in [256w, 256w+256).
// H state + flags move through IF$ via relaxed SYSTEM-scope atomics (sc0 sc1).
__global__ __launch_bounds__(256) void rnn_kernel(
    const unsigned short* __restrict__ Wrt,   // [N][K] bf16
    const float* __restrict__ Xpre,           // [S][32][1024] f32
    unsigned short* __restrict__ Hext,        // [(S+1)][32][1024] bf16
    int* __restrict__ flags) {                // [NBLK] progress flags
  __shared__ unsigned short wlds[NBLK * 1024];       // 64 KB W-slice fragments
  __shared__ float part[4][32][32];                  // 16 KB K-split partials
  const int tid  = threadIdx.x;
  const int lane = tid & 63;
  const int w    = tid >> 6;   // wave id = K-quarter
  const int cl   = lane & 15;
  const int rq   = lane >> 4;
  const int n0   = blockIdx.x * 32;
  const int bid  = blockIdx.x;

  // stage W fragments for this wave's K-quarter (one-time)
#pragma unroll
  for (int g = 0; g < 8; ++g) {
    const int ga = w * 8 + g;
#pragma unroll
    for (int j = 0; j < 2; ++j) {
      const int n = n0 + j * 16 + cl;
      const int k = ga * 32 + rq * 8;
      *reinterpret_cast<short8*>(&wlds[(size_t)((ga * 2 + j) * 64 + lane) * 8]) =
          *reinterpret_cast<const short8*>(&Wrt[(size_t)n * D_MOD + k]);
    }
  }
  __syncthreads();

  // reduction-thread mapping: thread -> (row rr, col group c4)
  const int rr = tid >> 3;         // 0..31
  const int c4 = (tid & 7) * 4;    // 0,4,..,28
  float4 xv = *reinterpret_cast<const float4*>(&Xpre[(size_t)rr * D_MOD + n0 + c4]);

  union U8 { short8 s; unsigned long long u[2]; };

  for (int t = 0; t < S_LEN; ++t) {
    if (t > 0) {
      if (w == 0) {
        // lanes 0..63 poll flags[lane&31] (coalesced 128B sc-bypass load)
        while (true) {
          int f = __hip_atomic_load(&flags[lane & 31], __ATOMIC_RELAXED,
                                    __HIP_MEMORY_SCOPE_SYSTEM);
          if (__all(f >= t)) break;
        }
      }
      __syncthreads();
    }
    const unsigned short* Hp = Hext + (size_t)t * B_SZ * D_MOD;

    floatx4 acc[2][2] = {};
#pragma unroll
    for (int g = 0; g < 8; ++g) {
      const int ga = w * 8 + g;
      const int k  = ga * 32 + rq * 8;
      U8 a0, a1;
      unsigned long long* p0 = (unsigned long long*)(Hp + (size_t)cl * D_MOD + k);
      unsigned long long* p1 = (unsigned long long*)(Hp + (size_t)(16 + cl) * D_MOD + k);
      a0.u[0] = __hip_atomic_load(p0,     __ATOMIC_RELAXED, __HIP_MEMORY_SCOPE_SYSTEM);
      a0.u[1] = __hip_atomic_load(p0 + 1, __ATOMIC_RELAXED, __HIP_MEMORY_SCOPE_SYSTEM);
      a1.u[0] = __hip_atomic_load(p1,     __ATOMIC_RELAXED, __HIP_MEMORY_SCOPE_SYSTEM);
      a1.u[1] = __hip_atomic_load(p1 + 1, __ATOMIC_RELAXED, __HIP_MEMORY_SCOPE_SYSTEM);
      short8 b0 = *reinterpret_cast<const short8*>(&wlds[(size_t)((ga * 2 + 0) * 64 + lane) * 8]);
      short8 b1 = *reinterpret_cast<const short8*>(&wlds[(size_t)((ga * 2 + 1) * 64 + lane) * 8]);
      acc[0][0] = __builtin_amdgcn_mfma_f32_16x16x32_bf16(a0.s, b0, acc[0][0], 0, 0, 0);
      acc[0][1] = __builtin_amdgcn_mfma_f32_16x16x32_bf16(a1.s, b0, acc[0][1], 0, 0, 0);
      acc[1][0] = __builtin_amdgcn_mfma_f32_16x16x32_bf16(a0.s, b1, acc[1][0], 0, 0, 0);
      acc[1][1] = __builtin_amdgcn_mfma_f32_16x16x32_bf16(a1.s, b1, acc[1][1], 0, 0, 0);
    }

    // write K-partials to LDS
#pragma unroll
    for (int j = 0; j < 2; ++j)
#pragma unroll
      for (int h = 0; h < 2; ++h)
#pragma unroll
        for (int r = 0; r < 4; ++r)
          part[w][h * 16 + rq * 4 + r][j * 16 + cl] = acc[j][h][r];
    __syncthreads();

    // reduce across K-quarters + bias-preadded Xpre + tanh -> bf16 store (8B)
    const float* pr = &part[0][rr][c4];
    float4 s0 = *reinterpret_cast<const float4*>(pr);
    float4 s1 = *reinterpret_cast<const float4*>(pr + 1024);
    float4 s2 = *reinterpret_cast<const float4*>(pr + 2048);
    float4 s3 = *reinterpret_cast<const float4*>(pr + 3072);
    float vx = tanh_fast(s0.x + s1.x + s2.x + s3.x + xv.x);
    float vy = tanh_fast(s0.y + s1.y + s2.y + s3.y + xv.y);
    float vz = tanh_fast(s0.z + s1.z + s2.z + s3.z + xv.z);
    float vw = tanh_fast(s0.w + s1.w + s2.w + s3.w + xv.w);
    unsigned long long pv =
        (unsigned long long)f2bf(vx)
      | ((unsigned long long)f2bf(vy) << 16)
      | ((unsigned long long)f2bf(vz) << 32)
      | ((unsigned long long)f2bf(vw) << 48);
    unsigned short* Hn = Hext + (size_t)(t + 1) * B_SZ * D_MOD;
    __hip_atomic_store((unsigned long long*)(Hn + (size_t)rr * D_MOD + n0 + c4), pv,
                       __ATOMIC_RELAXED, __HIP_MEMORY_SCOPE_SYSTEM);

    // prefetch next step's Xpre during the barrier interval (plain cached load)
    if (t + 1 < S_LEN)
      xv = *reinterpret_cast<const float4*>(
          &Xpre[(size_t)(t + 1) * B_SZ * D_MOD + rr * D_MOD + n0 + c4]);

    __syncthreads();  // drains each wave's vmcnt before s_barrier -> H visible
    if (tid == 0)
      __hip_atomic_store(&flags[bid], t + 1, __ATOMIC_RELAXED,
                         __HIP_MEMORY_SCOPE_SYSTEM);
  }
}

extern "C" void kernel_launch(void* const* d_in, const int* in_sizes, int n_in,
                              void* d_out, int out_size, void* d_ws, size_t ws_size,
                              hipStream_t stream) {
  const float* src   = (const float*)d_in[0];
  const float* W_in  = (const float*)d_in[1];
  const float* W_rec = (const float*)d_in[2];
  const float* W_out = (const float*)d_in[3];
  const float* b_h   = (const float*)d_in[4];
  const float* b_o   = (const float*)d_in[5];
  float* out = (float*)d_out;

  char* ws = (char*)d_ws;
  unsigned short* src_bf = (unsigned short*)ws; ws += (size_t)M_TOT * D_MOD * 2;
  unsigned short* Wt_in  = (unsigned short*)ws; ws += (size_t)D_MOD * D_MOD * 2;
  unsigned short* Wt_rec = (unsigned short*)ws; ws += (size_t)D_MOD * D_MOD * 2;
  unsigned short* Wt_out = (unsigned short*)ws; ws += (size_t)D_MOD * D_MOD * 2;
  float*          Xpre   = (float*)ws;          ws += (size_t)M_TOT * D_MOD * 4;
  unsigned short* Hext   = (unsigned short*)ws; ws += (size_t)(S_LEN + 1) * B_SZ * D_MOD * 2;
  int*            flags  = (int*)ws;            // [NBLK] progress flags

  convert_src_kernel<<<(M_TOT * D_MOD / 4 + 255) / 256, 256, 0, stream>>>(
      src, src_bf, M_TOT * D_MOD);
  dim3 tg(32, 32);
  transpose_w_kernel<<<tg, 256, 0, stream>>>(W_in,  Wt_in);
  transpose_w_kernel<<<tg, 256, 0, stream>>>(W_rec, Wt_rec);
  transpose_w_kernel<<<tg, 256, 0, stream>>>(W_out, Wt_out);
  hipMemsetAsync(Hext, 0, (size_t)B_SZ * D_MOD * 2, stream);  // h0 = 0
  hipMemsetAsync(flags, 0, 128, stream);                      // flags = 0

  dim3 g1(D_MOD / BN, M_TOT / BM);
  gemm_bias_kernel<<<g1, 256, 0, stream>>>(src_bf, Wt_in, b_h, Xpre, M_TOT, D_MOD, D_MOD);

  rnn_kernel<<<NBLK, 256, 0, stream>>>(Wt_rec, Xpre, Hext, flags);

  gemm_bias_kernel<<<g1, 256, 0, stream>>>(
      Hext + (size_t)B_SZ * D_MOD, Wt_out, b_o, out, M_TOT, D_MOD, D_MOD);
}